// Round 4
// baseline (267.900 us; speedup 1.0000x reference)
//
#include <hip/hip_runtime.h>
#include <hip/hip_bf16.h>

// RangeLoss: mean((preds - adjusted_target)^2) over 8M x 4 fp32.
// Memory-bound streaming reduction: 256 MB read, 1 float out.
// Two-stage deterministic reduction: per-block partials -> final block.

#define BLOCK 256
#define GRID 2048
#define CR 0.05f

__global__ __launch_bounds__(BLOCK) void range_loss_partial(
    const float4* __restrict__ preds,
    const float4* __restrict__ targ,
    float* __restrict__ partials,
    int nrows)
{
    int tid = blockIdx.x * BLOCK + threadIdx.x;
    int stride = gridDim.x * BLOCK;

    float acc = 0.0f;
    for (int i = tid; i < nrows; i += stride) {
        float4 p = preds[i];
        float4 t = targ[i];

        // --- _adjust_target, columns 0 and 1 (sequential semantics) ---
        float t0 = t.x;
        if (fabsf(p.x) < 0.01f && t0 == 0.0f) t0 = p.x;
        if (p.x > 0.99f && p.x < 1.01f && t0 == 1.0f) t0 = p.x;

        float t1 = t.y;
        if (fabsf(p.y) < 0.01f && t1 == 0.0f) t1 = p.y;
        if (p.y > 0.99f && p.y < 1.01f && t1 == 1.0f) t1 = p.y;

        // --- confidence-range override on column 1 (reads adjusted t1) ---
        bool cond_hi  = p.z > 0.9f;
        bool cond_rng = (p.y * (1.0f + CR) > t1) && (p.y * (1.0f - CR) < t1);
        if (cond_hi || cond_rng) t1 = p.y;

        float d0 = p.x - t0;
        float d1 = p.y - t1;
        float d2 = p.z - t.z;
        float d3 = p.w - t.w;
        acc += d0 * d0 + d1 * d1 + d2 * d2 + d3 * d3;
    }

    // wave (64-lane) reduction
    for (int off = 32; off > 0; off >>= 1)
        acc += __shfl_down(acc, off);

    __shared__ float smem[BLOCK / 64];
    int lane = threadIdx.x & 63;
    int wave = threadIdx.x >> 6;
    if (lane == 0) smem[wave] = acc;
    __syncthreads();

    if (threadIdx.x == 0) {
        float s = 0.0f;
        #pragma unroll
        for (int w = 0; w < BLOCK / 64; ++w) s += smem[w];
        partials[blockIdx.x] = s;
    }
}

__global__ __launch_bounds__(BLOCK) void range_loss_final(
    const float* __restrict__ partials,
    int nparts,
    float* __restrict__ out,
    double inv_n)
{
    double acc = 0.0;
    for (int i = threadIdx.x; i < nparts; i += BLOCK)
        acc += (double)partials[i];

    for (int off = 32; off > 0; off >>= 1)
        acc += __shfl_down(acc, off);

    __shared__ double smem[BLOCK / 64];
    int lane = threadIdx.x & 63;
    int wave = threadIdx.x >> 6;
    if (lane == 0) smem[wave] = acc;
    __syncthreads();

    if (threadIdx.x == 0) {
        double s = 0.0;
        #pragma unroll
        for (int w = 0; w < BLOCK / 64; ++w) s += smem[w];
        out[0] = (float)(s * inv_n);
    }
}

extern "C" void kernel_launch(void* const* d_in, const int* in_sizes, int n_in,
                              void* d_out, int out_size, void* d_ws, size_t ws_size,
                              hipStream_t stream)
{
    const float4* preds = (const float4*)d_in[0];
    const float4* targ  = (const float4*)d_in[1];

    int n_elems = in_sizes[0];     // 32,000,000
    int nrows   = n_elems / 4;     // 8,000,000 rows of float4

    float* partials = (float*)d_ws;            // GRID floats = 8 KB scratch
    float* out      = (float*)d_out;

    double inv_n = 1.0 / (double)n_elems;

    range_loss_partial<<<GRID, BLOCK, 0, stream>>>(preds, targ, partials, nrows);
    range_loss_final<<<1, BLOCK, 0, stream>>>(partials, GRID, out, inv_n);
}